// Round 8
// baseline (374.056 us; speedup 1.0000x reference)
//
#include <hip/hip_runtime.h>
#include <hip/hip_bf16.h>

#define DM 1024
#define SEQ 2048
#define NBATCH 4

using f32x4 = __attribute__((ext_vector_type(4))) float;
using s16x8 = __attribute__((ext_vector_type(8))) short;   // 8 bf16 in 4 VGPRs
using u16x4 = __attribute__((ext_vector_type(4))) unsigned short;
using u16x8 = __attribute__((ext_vector_type(8))) unsigned short;

__device__ __forceinline__ unsigned short f2bf(float f) {
  union { float f; unsigned u; } v; v.f = f;
  return (unsigned short)((v.u + 0x7fffu + ((v.u >> 16) & 1u)) >> 16);  // RNE
}

// ---------------- fused prep: x->bf16 cast  +  W transpose/cast ----------------
__global__ void prep_k(const float* __restrict__ X,
                       const float* __restrict__ Wq, const float* __restrict__ Wk,
                       const float* __restrict__ Wv,
                       unsigned short* __restrict__ XB, unsigned short* __restrict__ WT) {
  __shared__ float t[32][33];
  const int b = blockIdx.x;
  if (b < 4096) {
    const int i = b * 256 + threadIdx.x;
    const f32x4* p = (const f32x4*)X;
    f32x4 a = p[2 * i], c = p[2 * i + 1];
    u16x8 o;
#pragma unroll
    for (int q = 0; q < 4; q++) { o[q] = f2bf(a[q]); o[4 + q] = f2bf(c[q]); }
    *(u16x8*)(XB + (size_t)i * 8) = o;
  } else {
    const int r2 = b - 4096;
    const int seg = r2 >> 10;
    const int rem = r2 & 1023;
    const int k0 = (rem >> 5) * 32, n0 = (rem & 31) * 32;
    const float* W = (seg == 0) ? Wq : (seg == 1) ? Wk : Wv;
    unsigned short* out = WT + (size_t)seg * DM * DM;
    const int tr = threadIdx.x >> 5, tc = threadIdx.x & 31;
#pragma unroll
    for (int p = 0; p < 4; p++) {
      int r = tr + p * 8;
      t[r][tc] = W[(size_t)(k0 + r) * DM + n0 + tc];
    }
    __syncthreads();
#pragma unroll
    for (int p = 0; p < 4; p++) {
      int r = tr + p * 8;
      out[(size_t)(n0 + r) * DM + k0 + tc] = f2bf(t[tc][r]);
    }
  }
}

// softmax-combine: fold 16 tile stats into scale table, TRANSPOSED T[t][idx].
// sv is SPLIT: 32 entries/row (2 wave-halves per tile), folded here.
__global__ void combine_k(const float* __restrict__ ms, const float* __restrict__ ss,
                          float* __restrict__ T) {
  const int idx = blockIdx.x * 256 + threadIdx.x;     // 0..8191
  const float* m = ms + (size_t)idx * 16;
  const float* s = ss + (size_t)idx * 32;
  float mv[16];
#pragma unroll
  for (int t = 0; t < 16; t++) mv[t] = m[t];
  float M = mv[0];
#pragma unroll
  for (int t = 1; t < 16; t++) M = fmaxf(M, mv[t]);
  float L = 0.f;
#pragma unroll
  for (int t = 0; t < 16; t++) L += (s[2 * t] + s[2 * t + 1]) * __expf(mv[t] - M);
  T[idx] = 1.0f;
#pragma unroll
  for (int t = 1; t < 16; t++) T[t * 8192 + idx] = __expf(mv[t - 1] - mv[t]);
  T[16 * 8192 + idx] = __expf(mv[15] - M) / L;
}

// ---------------- bf16 NT GEMM: 128x128 tile, BK=64, 3-stage pipeline ----------------
// LDS double-buffer (2x32KB) + register staging; ONE raw barrier per K-iter:
//   iter k: WRITET(buf[(k+1)&1])   [vmcnt wait for loads issued a FULL iter ago]
//           LOADT(k+2)             [in flight across the barrier]
//           compute buf[k&1]       [ds_read+MFMA overlap the ds_writes above]
//           lgkm-wait + s_barrier  [raw: vmem loads stay outstanding]
// Buffer hazards: write of tile k+1 targets the buffer all waves finished
// reading at the previous barrier; reads of tile k follow the barrier that
// ordered its writes.  XOR swizzle key=row&7 (conflict-free b128 r/w).
// XCD-aware 1D grid: bid -> (xcd=bid&7, slot=bid>>3); per-XCD private patch.
// MODE 0: QKV  MODE 1: S-gemm + split-softmax epilogue  MODE 2: telescoped PV
template <int MODE, int LDA, int LDB, int KDIM>
__global__ void gemm_nt(const unsigned short* __restrict__ A,
                        const unsigned short* __restrict__ B,
                        void* __restrict__ C0,
                        unsigned short* __restrict__ C1,
                        unsigned short* __restrict__ C2,
                        const float* __restrict__ bq,
                        const float* __restrict__ bk,
                        const float* __restrict__ bv,
                        float* __restrict__ sm,
                        float* __restrict__ sv,
                        const float* __restrict__ Tt) {
  __shared__ unsigned short lbuf[32768];    // 64 KB: two 32KB stages (lA|lB each)

  const int tid = threadIdx.x;
  const int w = tid >> 6;
  const int L = tid & 63;
  const int wm = w & 1, wn = w >> 1;
  const int qd = L >> 4, ll = L & 15;

  // ---- XCD-aware tile mapping ----
  const int bid = blockIdx.x;
  const int xcd = bid & 7, slot = bid >> 3;
  int bz, tileM, tileN, nT;
  if (MODE == 0) {
    const int pm = xcd & 3, pn = xcd >> 2;        // 4 M-quarters x 2 N-halves
    const int nloc = slot % 12, mloc = slot / 12; // 192 slots, n-fastest
    bz = 0; tileM = (pm * 16 + mloc) * 128; tileN = (pn * 12 + nloc) * 128; nT = 0;
  } else if (MODE == 1) {
    bz = xcd >> 1;
    const int mh = xcd & 1;
    const int nloc = slot & 15, mloc = slot >> 4; // 128 slots
    tileM = (mh * 8 + mloc) * 128; tileN = nloc * 128; nT = nloc;
  } else {
    bz = xcd >> 1;
    const int mh = xcd & 1;
    const int nloc = slot & 7, mloc = slot >> 3;  // 64 slots
    tileM = (mh * 8 + mloc) * 128; tileN = nloc * 128; nT = nloc;
  }

  const unsigned short* Ab = A;
  const unsigned short* Bb = B;
  if (MODE == 1) { Ab += (size_t)bz * SEQ * DM; Bb += (size_t)bz * SEQ * DM; }
  if (MODE == 2) { Ab += (size_t)bz * SEQ * SEQ; Bb += (size_t)bz * DM * SEQ; }

  // staging geometry: thread t -> row srow=t>>3 (0..31, +32*i), phys chunk t&7,
  // global chunk = (t&7) ^ (row&7).
  const int srow = tid >> 3;
  const int pch = tid & 7;
  const int gch = pch ^ (srow & 7);
  const unsigned short* gA = Ab + (size_t)(tileM + srow) * LDA + gch * 8;
  const unsigned short* gB = Bb + (size_t)(tileN + srow) * LDB + gch * 8;
  unsigned short* wA0 = &lbuf[srow * 64 + pch * 8];          // buffer 0, A half
  unsigned short* wB0 = wA0 + 8192;                          // buffer 0, B half

  u16x8 rA[4], rB[4];
#define LOADT(kt) do {                                                         \
    const size_t kk_ = (size_t)(kt) * 64;                                      \
    _Pragma("unroll")                                                          \
    for (int i_ = 0; i_ < 4; i_++) {                                           \
      rA[i_] = *(const u16x8*)(gA + (size_t)i_ * 32 * LDA + kk_);              \
      rB[i_] = *(const u16x8*)(gB + (size_t)i_ * 32 * LDB + kk_);              \
    }                                                                          \
  } while (0)
#define WRITET(b) do {                                                         \
    unsigned short* wa_ = wA0 + (b) * 16384;                                   \
    unsigned short* wb_ = wB0 + (b) * 16384;                                   \
    _Pragma("unroll")                                                          \
    for (int i_ = 0; i_ < 4; i_++) {                                           \
      *(u16x8*)(wa_ + i_ * 32 * 64) = rA[i_];                                  \
      *(u16x8*)(wb_ + i_ * 32 * 64) = rB[i_];                                  \
    }                                                                          \
  } while (0)
#define RAWBAR() do {                                                          \
    __builtin_amdgcn_s_waitcnt(0xC07F);        /* lgkmcnt(0) only */           \
    __builtin_amdgcn_sched_barrier(0);                                         \
    __builtin_amdgcn_s_barrier();                                              \
    __builtin_amdgcn_sched_barrier(0);                                         \
  } while (0)

  f32x4 acc[4][4];
#pragma unroll
  for (int i = 0; i < 4; i++)
#pragma unroll
    for (int j = 0; j < 4; j++) acc[i][j] = (f32x4){0.f, 0.f, 0.f, 0.f};

  const int sw = L & 7;         // swizzle key for fragment rows

  // MODE2: prefetched scale-table values (broadcast-coalesced layout)
  float tTn[4][4];
  const float* Tb = nullptr;
  if (MODE == 2) {
    Tb = Tt + (size_t)bz * SEQ + tileM + wm * 64;
#pragma unroll
    for (int i = 0; i < 4; i++)
#pragma unroll
      for (int r = 0; r < 4; r++) tTn[i][r] = Tb[1 * 8192 + i * 16 + qd * 4 + r];
  }

  constexpr int NK = KDIM / 64;
  LOADT(0);
  WRITET(0);                     // vmcnt wait (one-time preamble exposure)
  LOADT(1);
  RAWBAR();                      // loads for tile 1 stay in flight

  for (int k = 0; k < NK; ++k) {
    if (k + 1 < NK) WRITET((k + 1) & 1);  // waits vmcnt for LOADT(k+1): full-iter cover

    if (MODE == 2 && k >= 2 && (k & 1) == 0) {
      // tile boundary t=k/2: rescale acc by T[t] (in tTn), prefetch T[t+1]
#pragma unroll
      for (int i = 0; i < 4; i++)
#pragma unroll
        for (int j = 0; j < 4; j++)
#pragma unroll
          for (int r = 0; r < 4; r++) acc[i][j][r] *= tTn[i][r];
      const int tn = (k >> 1) + 1;
#pragma unroll
      for (int i = 0; i < 4; i++)
#pragma unroll
        for (int r = 0; r < 4; r++) tTn[i][r] = Tb[(size_t)tn * 8192 + i * 16 + qd * 4 + r];
    }

    if (k + 2 < NK) LOADT(k + 2);         // in flight across compute + barrier

    const unsigned short* cA = lbuf + (k & 1) * 16384;
    const unsigned short* cB = cA + 8192;
#pragma unroll
    for (int s = 0; s < 2; s++) {         // two K=32 halves of the BK=64 tile
      const int pc = ((s * 4 + qd) ^ sw) * 8;
      s16x8 av[4], bv4[4];
#pragma unroll
      for (int i = 0; i < 4; i++)
        av[i] = *(const s16x8*)&cA[(wm * 64 + i * 16 + ll) * 64 + pc];
#pragma unroll
      for (int j = 0; j < 4; j++)
        bv4[j] = *(const s16x8*)&cB[(wn * 64 + j * 16 + ll) * 64 + pc];
#pragma unroll
      for (int i = 0; i < 4; i++)
#pragma unroll
        for (int j = 0; j < 4; j++)
          acc[i][j] = __builtin_amdgcn_mfma_f32_16x16x32_bf16(av[i], bv4[j], acc[i][j], 0, 0, 0);
    }

    RAWBAR();                              // orders writes of k+1 / reuse of buffers
  }
#undef LOADT
#undef WRITET
#undef RAWBAR

  // ---------------- epilogues ----------------
  // C/D layout: col = wn*64 + j*16 + ll ; row = wm*64 + i*16 + qd*4 + r (local)
  if (MODE == 0) {
#pragma unroll
    for (int i = 0; i < 4; i++) {
      const int gm0 = tileM + wm * 64 + i * 16 + qd * 4;
#pragma unroll
      for (int j = 0; j < 4; j++) {
        const int gn = tileN + wn * 64 + j * 16 + ll;
        const int seg = gn >> 10;          // block-uniform
        const int colin = gn & 1023;
        if (seg == 0) {
          const float bias = bq[colin];
          unsigned short* Q = (unsigned short*)C0;
#pragma unroll
          for (int r = 0; r < 4; r++) Q[(size_t)(gm0 + r) * DM + colin] = f2bf(acc[i][j][r] + bias);
        } else if (seg == 1) {
          const float bias = bk[colin];
#pragma unroll
          for (int r = 0; r < 4; r++) C1[(size_t)(gm0 + r) * DM + colin] = f2bf(acc[i][j][r] + bias);
        } else {                            // V, stored transposed: Vt[b][d][s]
          const float bias = bv[colin];
          u16x4 pk;
#pragma unroll
          for (int r = 0; r < 4; r++) pk[r] = f2bf(acc[i][j][r] + bias);
          const int b = gm0 >> 11, s0 = gm0 & 2047;
          *(u16x4*)(C2 + ((size_t)((b << 10) + colin)) * SEQ + s0) = pk;
        }
      }
    }
  } else if (MODE == 1) {
    __syncthreads();                       // all waves done with K-loop LDS
    // scale by 1/32; per-wave (64-col) row max via shfl
    float mt[4][4];
#pragma unroll
    for (int i = 0; i < 4; i++)
#pragma unroll
      for (int r = 0; r < 4; r++) {
#pragma unroll
        for (int j = 0; j < 4; j++) acc[i][j][r] *= 0.03125f;
        float v = fmaxf(fmaxf(acc[i][0][r], acc[i][1][r]), fmaxf(acc[i][2][r], acc[i][3][r]));
#pragma unroll
        for (int m = 1; m < 16; m <<= 1) v = fmaxf(v, __shfl_xor(v, m, 16));
        mt[i][r] = v;
      }
    // cross-wave max exchange through lbuf head — consumed before P' writes
    float* fred = (float*)lbuf;            // 256 floats
    if (ll == 0) {
#pragma unroll
      for (int i = 0; i < 4; i++)
#pragma unroll
        for (int r = 0; r < 4; r++)
          fred[wn * 128 + wm * 64 + i * 16 + qd * 4 + r] = mt[i][r];
    }
    __syncthreads();
#pragma unroll
    for (int i = 0; i < 4; i++)
#pragma unroll
      for (int r = 0; r < 4; r++) {
        const int row = wm * 64 + i * 16 + qd * 4 + r;
        mt[i][r] = fmaxf(fred[row], fred[128 + row]);
      }
    __syncthreads();                       // mt in regs; lbuf now free for P'
    // exp; P' bf16 into lbuf (swizzled); per-wave partial sums straight to sv
#pragma unroll
    for (int i = 0; i < 4; i++)
#pragma unroll
      for (int r = 0; r < 4; r++) {
        const int row = wm * 64 + i * 16 + qd * 4 + r;
        float s = 0.f;
#pragma unroll
        for (int j = 0; j < 4; j++) {
          float e = __expf(acc[i][j][r] - mt[i][r]);
          s += e;
          const int col = wn * 64 + j * 16 + ll;
          lbuf[row * 128 + ((((col >> 4) ^ (row & 7)) << 4) | (col & 15))] = f2bf(e);
        }
#pragma unroll
        for (int m = 1; m < 16; m <<= 1) s += __shfl_xor(s, m, 16);
        if (ll == 0) {
          const size_t base = (size_t)bz * SEQ + tileM + row;
          sv[base * 32 + nT * 2 + wn] = s;
          if (wn == 0) sm[base * 16 + nT] = mt[i][r];
        }
      }
    __syncthreads();                       // lbuf complete
    // coalesced P' store: 8 x u16x8 per thread
    unsigned short* P = (unsigned short*)C0 + (size_t)bz * SEQ * SEQ;
#pragma unroll
    for (int p = 0; p < 8; p++) {
      const int c = p * 256 + tid;
      const int row = c >> 4, cg = c & 15;
      const int phys = ((((cg >> 1) ^ (row & 7)) << 4) | ((cg & 1) << 3));
      u16x8 val = *(const u16x8*)&lbuf[row * 128 + phys];
      *(u16x8*)(P + (size_t)(tileM + row) * SEQ + tileN + cg * 8) = val;
    }
  } else {
    // final scale T[16] (in tTn), store fp32
    float* O = (float*)C0 + (size_t)bz * SEQ * DM;
#pragma unroll
    for (int i = 0; i < 4; i++) {
      const int gm0 = tileM + wm * 64 + i * 16 + qd * 4;
#pragma unroll
      for (int j = 0; j < 4; j++) {
        const int gn = tileN + wn * 64 + j * 16 + ll;
#pragma unroll
        for (int r = 0; r < 4; r++)
          O[(size_t)(gm0 + r) * DM + gn] = acc[i][j][r] * tTn[i][r];
      }
    }
  }
}

// ---------------- launch ----------------
// ws layout (bytes):
//   xb  @ 0         : 16 MB   bf16 x       [8192,1024]
//   wt  @ 16777216  :  6 MB   bf16 W^T     [3072,1024]
//   qb  @ 23068672  : 16 MB   bf16 Q       [8192,1024]
//   kb  @ 39845888  : 16 MB   bf16 K       [8192,1024]
//   vt  @ 56623104  : 16 MB   bf16 V^T     [4][1024][2048]
//   P   @ 73400320  : 32 MB   bf16 P'      [4][2048][2048]
//   ms  @ 106954752 : 512 KB  fp32 stats m [4][2048][16]
//   ss  @ 107479040 : 1 MB    fp32 stats s [4][2048][32]  (split per wave-half)
//   T   @ 108527616 : 544 KB  fp32 scale   [17][4*2048]   (transposed)
// total ~109 MB
extern "C" void kernel_launch(void* const* d_in, const int* in_sizes, int n_in,
                              void* d_out, int out_size, void* d_ws, size_t ws_size,
                              hipStream_t stream) {
  (void)in_sizes; (void)n_in; (void)out_size; (void)ws_size;
  const float* x  = (const float*)d_in[0];
  const float* Wq = (const float*)d_in[1];
  const float* bq = (const float*)d_in[2];
  const float* Wk = (const float*)d_in[3];
  const float* bk = (const float*)d_in[4];
  const float* Wv = (const float*)d_in[5];
  const float* bv = (const float*)d_in[6];
  float* out = (float*)d_out;
  char* ws = (char*)d_ws;
  unsigned short* xb = (unsigned short*)(ws + 0);
  unsigned short* wt = (unsigned short*)(ws + 16777216);
  unsigned short* qb = (unsigned short*)(ws + 23068672);
  unsigned short* kb = (unsigned short*)(ws + 39845888);
  unsigned short* vt = (unsigned short*)(ws + 56623104);
  unsigned short* P  = (unsigned short*)(ws + 73400320);
  float*          ms = (float*)(ws + 106954752);
  float*          ss = (float*)(ws + 107479040);
  float*          Tt = (float*)(ws + 108527616);

  prep_k<<<7168, 256, 0, stream>>>(x, Wq, Wk, Wv, xb, wt);
  gemm_nt<0, 1024, 1024, 1024><<<1536, 256, 0, stream>>>(
      xb, wt, (void*)qb, kb, vt, bq, bk, bv, nullptr, nullptr, nullptr);
  gemm_nt<1, 1024, 1024, 1024><<<1024, 256, 0, stream>>>(
      qb, kb, (void*)P, nullptr, nullptr, nullptr, nullptr, nullptr, ms, ss, nullptr);
  combine_k<<<32, 256, 0, stream>>>(ms, ss, Tt);
  gemm_nt<2, 2048, 2048, 2048><<<512, 256, 0, stream>>>(
      P, vt, (void*)out, nullptr, nullptr, nullptr, nullptr, nullptr, nullptr, nullptr, Tt);
}

// Round 9
// 253.457 us; speedup vs baseline: 1.4758x; 1.4758x over previous
//
#include <hip/hip_runtime.h>
#include <hip/hip_bf16.h>

#define DM 1024
#define SEQ 2048
#define NBATCH 4

using f32x4 = __attribute__((ext_vector_type(4))) float;
using s16x8 = __attribute__((ext_vector_type(8))) short;   // 8 bf16 in 4 VGPRs
using u16x4 = __attribute__((ext_vector_type(4))) unsigned short;
using u16x8 = __attribute__((ext_vector_type(8))) unsigned short;

__device__ __forceinline__ unsigned short f2bf(float f) {
  union { float f; unsigned u; } v; v.f = f;
  return (unsigned short)((v.u + 0x7fffu + ((v.u >> 16) & 1u)) >> 16);  // RNE
}

// ---------------- fused prep: x->bf16 cast  +  W transpose/cast ----------------
__global__ void prep_k(const float* __restrict__ X,
                       const float* __restrict__ Wq, const float* __restrict__ Wk,
                       const float* __restrict__ Wv,
                       unsigned short* __restrict__ XB, unsigned short* __restrict__ WT) {
  __shared__ float t[32][33];
  const int b = blockIdx.x;
  if (b < 4096) {
    const int i = b * 256 + threadIdx.x;
    const f32x4* p = (const f32x4*)X;
    f32x4 a = p[2 * i], c = p[2 * i + 1];
    u16x8 o;
#pragma unroll
    for (int q = 0; q < 4; q++) { o[q] = f2bf(a[q]); o[4 + q] = f2bf(c[q]); }
    *(u16x8*)(XB + (size_t)i * 8) = o;
  } else {
    const int r2 = b - 4096;
    const int seg = r2 >> 10;
    const int rem = r2 & 1023;
    const int k0 = (rem >> 5) * 32, n0 = (rem & 31) * 32;
    const float* W = (seg == 0) ? Wq : (seg == 1) ? Wk : Wv;
    unsigned short* out = WT + (size_t)seg * DM * DM;
    const int tr = threadIdx.x >> 5, tc = threadIdx.x & 31;
#pragma unroll
    for (int p = 0; p < 4; p++) {
      int r = tr + p * 8;
      t[r][tc] = W[(size_t)(k0 + r) * DM + n0 + tc];
    }
    __syncthreads();
#pragma unroll
    for (int p = 0; p < 4; p++) {
      int r = tr + p * 8;
      out[(size_t)(n0 + r) * DM + k0 + tc] = f2bf(t[tc][r]);
    }
  }
}

// softmax-combine: fold 16 tile stats into scale table, TRANSPOSED T[t][idx].
// sv is SPLIT: 32 entries/row (2 wave-halves per tile), folded here.
__global__ void combine_k(const float* __restrict__ ms, const float* __restrict__ ss,
                          float* __restrict__ T) {
  const int idx = blockIdx.x * 256 + threadIdx.x;     // 0..8191
  const float* m = ms + (size_t)idx * 16;
  const float* s = ss + (size_t)idx * 32;
  float mv[16];
#pragma unroll
  for (int t = 0; t < 16; t++) mv[t] = m[t];
  float M = mv[0];
#pragma unroll
  for (int t = 1; t < 16; t++) M = fmaxf(M, mv[t]);
  float L = 0.f;
#pragma unroll
  for (int t = 0; t < 16; t++) L += (s[2 * t] + s[2 * t + 1]) * __expf(mv[t] - M);
  T[idx] = 1.0f;
#pragma unroll
  for (int t = 1; t < 16; t++) T[t * 8192 + idx] = __expf(mv[t - 1] - mv[t]);
  T[16 * 8192 + idx] = __expf(mv[15] - M) / L;
}

// ------- bf16 NT GEMM: BMx128 tile, BK=64, reg-staged two-barrier K-loop -------
// ROUND-4 PROVEN K-loop (r8's 3-stage spilled to scratch — do not revisit):
//   iter k: LOADT(k+1) -> compute buf (tile k) -> raw lgkm-barrier ->
//           WRITET (vmcnt wait lands here, after full compute cover) -> barrier.
// XOR swizzle key=row&7: conflict-free b128 LDS r/w (0 conflicts verified).
// XCD-aware 1D grid: bid -> (xcd=bid&7, slot=bid>>3); per-XCD private patch
// (verified: FETCH 150->43 MB on MODE1).
// MODE 0 (BM=128): QKV.  MODE 1 (BM=128): S-gemm + split-softmax epilogue.
// MODE 2 (BM=64): telescoped PV; 64-row tiles double block count (TLP fix).
template <int MODE, int BM, int LDA, int LDB, int KDIM>
__global__ void gemm_nt(const unsigned short* __restrict__ A,
                        const unsigned short* __restrict__ B,
                        void* __restrict__ C0,
                        unsigned short* __restrict__ C1,
                        unsigned short* __restrict__ C2,
                        const float* __restrict__ bq,
                        const float* __restrict__ bk,
                        const float* __restrict__ bv,
                        float* __restrict__ sm,
                        float* __restrict__ sv,
                        const float* __restrict__ Tt) {
  constexpr int ASTEPS = BM / 32;                 // staging steps for A (B fixed 4)
  constexpr int NJ = (BM == 128) ? 4 : 2;         // j-fragments per wave
  constexpr int WNOFF = 16 * NJ;                  // wave n-span
  __shared__ unsigned short lbuf[(BM + 128) * 64];  // A | B halves
  __shared__ float fred[256];                     // MODE1 stats exchange

  const int tid = threadIdx.x;
  const int w = tid >> 6;
  const int L = tid & 63;
  const int wm = (BM == 128) ? (w & 1) : 0;
  const int wn = (BM == 128) ? (w >> 1) : w;
  const int qd = L >> 4, ll = L & 15;

  // ---- XCD-aware tile mapping ----
  const int bid = blockIdx.x;
  const int xcd = bid & 7, slot = bid >> 3;
  int bz, tileM, tileN, nT;
  if (MODE == 0) {
    const int pm = xcd & 3, pn = xcd >> 2;        // 4 M-quarters x 2 N-halves
    const int nloc = slot % 12, mloc = slot / 12; // 192 slots, n-fastest
    bz = 0; tileM = (pm * 16 + mloc) * 128; tileN = (pn * 12 + nloc) * 128; nT = 0;
  } else if (MODE == 1) {
    bz = xcd >> 1;
    const int mh = xcd & 1;
    const int nloc = slot & 15, mloc = slot >> 4; // 128 slots
    tileM = (mh * 8 + mloc) * 128; tileN = nloc * 128; nT = nloc;
  } else {
    bz = xcd >> 1;
    const int mh = xcd & 1;                       // M-half (16 x 64-row tiles)
    const int nloc = slot & 7, mloc = slot >> 3;  // 128 slots
    tileM = (mh * 16 + mloc) * 64; tileN = nloc * 128; nT = nloc;
  }
  (void)nT;

  const unsigned short* Ab = A;
  const unsigned short* Bb = B;
  if (MODE == 1) { Ab += (size_t)bz * SEQ * DM; Bb += (size_t)bz * SEQ * DM; }
  if (MODE == 2) { Ab += (size_t)bz * SEQ * SEQ; Bb += (size_t)bz * DM * SEQ; }

  // staging geometry: thread t -> row srow=t>>3 (0..31, +32*step), phys chunk
  // t&7, global chunk = (t&7) ^ (row&7).
  const int srow = tid >> 3;
  const int pch = tid & 7;
  const int gch = pch ^ (srow & 7);
  const unsigned short* gA = Ab + (size_t)(tileM + srow) * LDA + gch * 8;
  const unsigned short* gB = Bb + (size_t)(tileN + srow) * LDB + gch * 8;
  unsigned short* lA = lbuf;
  unsigned short* lB = lbuf + BM * 64;
  unsigned short* wAp = &lA[srow * 64 + pch * 8];
  unsigned short* wBp = &lB[srow * 64 + pch * 8];

  u16x8 rA[ASTEPS], rB[4];
#define LOADT(kt) do {                                                         \
    const size_t kk_ = (size_t)(kt) * 64;                                      \
    _Pragma("unroll")                                                          \
    for (int i_ = 0; i_ < ASTEPS; i_++)                                        \
      rA[i_] = *(const u16x8*)(gA + (size_t)i_ * 32 * LDA + kk_);              \
    _Pragma("unroll")                                                          \
    for (int i_ = 0; i_ < 4; i_++)                                             \
      rB[i_] = *(const u16x8*)(gB + (size_t)i_ * 32 * LDB + kk_);              \
  } while (0)
#define WRITET() do {                                                          \
    _Pragma("unroll")                                                          \
    for (int i_ = 0; i_ < ASTEPS; i_++) *(u16x8*)(wAp + i_ * 32 * 64) = rA[i_];\
    _Pragma("unroll")                                                          \
    for (int i_ = 0; i_ < 4; i_++)      *(u16x8*)(wBp + i_ * 32 * 64) = rB[i_];\
  } while (0)

  f32x4 acc[4][NJ];
#pragma unroll
  for (int i = 0; i < 4; i++)
#pragma unroll
    for (int j = 0; j < NJ; j++) acc[i][j] = (f32x4){0.f, 0.f, 0.f, 0.f};

  const int sw = L & 7;         // swizzle key for fragment rows

  // MODE2: prefetched scale-table values (broadcast-coalesced layout)
  float tTn[4][4];
  const float* Tb = nullptr;
  if (MODE == 2) {
    Tb = Tt + (size_t)bz * SEQ + tileM;           // wm==0 for BM=64
#pragma unroll
    for (int i = 0; i < 4; i++)
#pragma unroll
      for (int r = 0; r < 4; r++) tTn[i][r] = Tb[1 * 8192 + i * 16 + qd * 4 + r];
  }

  constexpr int NK = KDIM / 64;
  LOADT(0);
  WRITET();                      // vmcnt wait (one-time preamble exposure)
  __syncthreads();

  for (int k = 0; k < NK; ++k) {
    if (MODE == 2 && k >= 2 && (k & 1) == 0) {
      // tile boundary t=k/2: rescale acc by T[t] (in tTn), prefetch T[t+1]
#pragma unroll
      for (int i = 0; i < 4; i++)
#pragma unroll
        for (int j = 0; j < NJ; j++)
#pragma unroll
          for (int r = 0; r < 4; r++) acc[i][j][r] *= tTn[i][r];
      const int tn = (k >> 1) + 1;
#pragma unroll
      for (int i = 0; i < 4; i++)
#pragma unroll
        for (int r = 0; r < 4; r++) tTn[i][r] = Tb[(size_t)tn * 8192 + i * 16 + qd * 4 + r];
    }

    if (k + 1 < NK) LOADT(k + 1);     // global->VGPR, flies across compute

#pragma unroll
    for (int s = 0; s < 2; s++) {     // two K=32 halves of the BK=64 tile
      const int pc = ((s * 4 + qd) ^ sw) * 8;
      s16x8 av[4], bv4[NJ];
#pragma unroll
      for (int i = 0; i < 4; i++)
        av[i] = *(const s16x8*)&lA[(wm * 64 + i * 16 + ll) * 64 + pc];
#pragma unroll
      for (int j = 0; j < NJ; j++)
        bv4[j] = *(const s16x8*)&lB[(wn * WNOFF + j * 16 + ll) * 64 + pc];
#pragma unroll
      for (int i = 0; i < 4; i++)
#pragma unroll
        for (int j = 0; j < NJ; j++)
          acc[i][j] = __builtin_amdgcn_mfma_f32_16x16x32_bf16(av[i], bv4[j], acc[i][j], 0, 0, 0);
    }

    if (k + 1 < NK) {
      __builtin_amdgcn_s_waitcnt(0xC07F);       // lgkmcnt(0) only; vmem in flight
      __builtin_amdgcn_sched_barrier(0);
      __builtin_amdgcn_s_barrier();
      __builtin_amdgcn_sched_barrier(0);
      WRITET();                                  // vmcnt wait auto-inserted here
      __syncthreads();
    }
  }
#undef LOADT
#undef WRITET

  // ---------------- epilogues ----------------
  // C/D layout: col = wn*WNOFF + j*16 + ll ; row = wm*64 + i*16 + qd*4 + r
  if (MODE == 0) {
#pragma unroll
    for (int i = 0; i < 4; i++) {
      const int gm0 = tileM + wm * 64 + i * 16 + qd * 4;
#pragma unroll
      for (int j = 0; j < NJ; j++) {
        const int gn = tileN + wn * WNOFF + j * 16 + ll;
        const int seg = gn >> 10;          // block-uniform
        const int colin = gn & 1023;
        if (seg == 0) {
          const float bias = bq[colin];
          unsigned short* Q = (unsigned short*)C0;
#pragma unroll
          for (int r = 0; r < 4; r++) Q[(size_t)(gm0 + r) * DM + colin] = f2bf(acc[i][j][r] + bias);
        } else if (seg == 1) {
          const float bias = bk[colin];
#pragma unroll
          for (int r = 0; r < 4; r++) C1[(size_t)(gm0 + r) * DM + colin] = f2bf(acc[i][j][r] + bias);
        } else {                            // V, stored transposed: Vt[b][d][s]
          const float bias = bv[colin];
          u16x4 pk;
#pragma unroll
          for (int r = 0; r < 4; r++) pk[r] = f2bf(acc[i][j][r] + bias);
          const int b = gm0 >> 11, s0 = gm0 & 2047;
          *(u16x4*)(C2 + ((size_t)((b << 10) + colin)) * SEQ + s0) = pk;
        }
      }
    }
  } else if (MODE == 1) {
    __syncthreads();                       // sync0: all K-loop LDS reads done
    // scale by 1/32; per-wave (64-col) row max via shfl
    float mt[4][4];
#pragma unroll
    for (int i = 0; i < 4; i++)
#pragma unroll
      for (int r = 0; r < 4; r++) {
#pragma unroll
        for (int j = 0; j < NJ; j++) acc[i][j][r] *= 0.03125f;
        float v = fmaxf(fmaxf(acc[i][0][r], acc[i][1][r]), fmaxf(acc[i][2][r], acc[i][3][r]));
#pragma unroll
        for (int m = 1; m < 16; m <<= 1) v = fmaxf(v, __shfl_xor(v, m, 16));
        mt[i][r] = v;
      }
    if (ll == 0) {
#pragma unroll
      for (int i = 0; i < 4; i++)
#pragma unroll
        for (int r = 0; r < 4; r++)
          fred[wn * 128 + wm * 64 + i * 16 + qd * 4 + r] = mt[i][r];
    }
    __syncthreads();                       // sync1: fred complete
#pragma unroll
    for (int i = 0; i < 4; i++)
#pragma unroll
      for (int r = 0; r < 4; r++) {
        const int row = wm * 64 + i * 16 + qd * 4 + r;
        mt[i][r] = fmaxf(fred[row], fred[128 + row]);
      }
    // exp; P' bf16 into lbuf (swizzled); per-wave partial sums straight to sv
#pragma unroll
    for (int i = 0; i < 4; i++)
#pragma unroll
      for (int r = 0; r < 4; r++) {
        const int row = wm * 64 + i * 16 + qd * 4 + r;
        float s = 0.f;
#pragma unroll
        for (int j = 0; j < NJ; j++) {
          float e = __expf(acc[i][j][r] - mt[i][r]);
          s += e;
          const int col = wn * WNOFF + j * 16 + ll;
          lbuf[row * 128 + ((((col >> 4) ^ (row & 7)) << 4) | (col & 15))] = f2bf(e);
        }
#pragma unroll
        for (int m = 1; m < 16; m <<= 1) s += __shfl_xor(s, m, 16);
        if (ll == 0) {
          const size_t base = (size_t)bz * SEQ + tileM + row;
          sv[base * 32 + nT * 2 + wn] = s;
          if (wn == 0) sm[base * 16 + nT] = mt[i][r];
        }
      }
    __syncthreads();                       // sync2: lbuf complete
    // coalesced P' store: 8 x u16x8 per thread
    unsigned short* P = (unsigned short*)C0 + (size_t)bz * SEQ * SEQ;
#pragma unroll
    for (int p = 0; p < 8; p++) {
      const int c = p * 256 + tid;
      const int row = c >> 4, cg = c & 15;
      const int phys = ((((cg >> 1) ^ (row & 7)) << 4) | ((cg & 1) << 3));
      u16x8 val = *(const u16x8*)&lbuf[row * 128 + phys];
      *(u16x8*)(P + (size_t)(tileM + row) * SEQ + tileN + cg * 8) = val;
    }
  } else {
    // final scale T[16] (in tTn), store fp32
    float* O = (float*)C0 + (size_t)bz * SEQ * DM;
#pragma unroll
    for (int i = 0; i < 4; i++) {
      const int gm0 = tileM + i * 16 + qd * 4;         // wm==0
#pragma unroll
      for (int j = 0; j < NJ; j++) {
        const int gn = tileN + wn * WNOFF + j * 16 + ll;
#pragma unroll
        for (int r = 0; r < 4; r++)
          O[(size_t)(gm0 + r) * DM + gn] = acc[i][j][r] * tTn[i][r];
      }
    }
  }
}

// ---------------- launch ----------------
// ws layout (bytes):
//   xb  @ 0         : 16 MB   bf16 x       [8192,1024]
//   wt  @ 16777216  :  6 MB   bf16 W^T     [3072,1024]
//   qb  @ 23068672  : 16 MB   bf16 Q       [8192,1024]
//   kb  @ 39845888  : 16 MB   bf16 K       [8192,1024]
//   vt  @ 56623104  : 16 MB   bf16 V^T     [4][1024][2048]
//   P   @ 73400320  : 32 MB   bf16 P'      [4][2048][2048]
//   ms  @ 106954752 : 512 KB  fp32 stats m [4][2048][16]
//   ss  @ 107479040 : 1 MB    fp32 stats s [4][2048][32]  (split per wave-half)
//   T   @ 108527616 : 544 KB  fp32 scale   [17][4*2048]   (transposed)
// total ~109 MB
extern "C" void kernel_launch(void* const* d_in, const int* in_sizes, int n_in,
                              void* d_out, int out_size, void* d_ws, size_t ws_size,
                              hipStream_t stream) {
  (void)in_sizes; (void)n_in; (void)out_size; (void)ws_size;
  const float* x  = (const float*)d_in[0];
  const float* Wq = (const float*)d_in[1];
  const float* bq = (const float*)d_in[2];
  const float* Wk = (const float*)d_in[3];
  const float* bk = (const float*)d_in[4];
  const float* Wv = (const float*)d_in[5];
  const float* bv = (const float*)d_in[6];
  float* out = (float*)d_out;
  char* ws = (char*)d_ws;
  unsigned short* xb = (unsigned short*)(ws + 0);
  unsigned short* wt = (unsigned short*)(ws + 16777216);
  unsigned short* qb = (unsigned short*)(ws + 23068672);
  unsigned short* kb = (unsigned short*)(ws + 39845888);
  unsigned short* vt = (unsigned short*)(ws + 56623104);
  unsigned short* P  = (unsigned short*)(ws + 73400320);
  float*          ms = (float*)(ws + 106954752);
  float*          ss = (float*)(ws + 107479040);
  float*          Tt = (float*)(ws + 108527616);

  prep_k<<<7168, 256, 0, stream>>>(x, Wq, Wk, Wv, xb, wt);
  gemm_nt<0, 128, 1024, 1024, 1024><<<1536, 256, 0, stream>>>(
      xb, wt, (void*)qb, kb, vt, bq, bk, bv, nullptr, nullptr, nullptr);
  gemm_nt<1, 128, 1024, 1024, 1024><<<1024, 256, 0, stream>>>(
      qb, kb, (void*)P, nullptr, nullptr, nullptr, nullptr, nullptr, ms, ss, nullptr);
  combine_k<<<32, 256, 0, stream>>>(ms, ss, Tt);
  gemm_nt<2, 64, 2048, 2048, 2048><<<1024, 256, 0, stream>>>(
      P, vt, (void*)out, nullptr, nullptr, nullptr, nullptr, nullptr, nullptr, nullptr, Tt);
}